// Round 3
// baseline (232.991 us; speedup 1.0000x reference)
//
#include <hip/hip_runtime.h>
#include <hip/hip_bf16.h>

typedef __bf16 bf16x8_t __attribute__((ext_vector_type(8)));
typedef float floatx4_t __attribute__((ext_vector_type(4)));

#define H 128
#define BATCH 256
#define SEQ 1024
#define NROWS_TOTAL (BATCH * SEQ)            // 262144 rows of x
#define STEP_ELEMS 33521664.0f               // 256*1023*128
#define MAIN_WGS 512

// ws layout: [0, 32768)      : Dpack, bf16, MFMA-B-fragment order [kt][n][lane][j]
//            [32768, 32776)  : accum[2] = {step_sum, l2_sum}
//            [32776, 32780)  : ticket counter (uint)
//            [65536, 131072) : T = A*A, fp32 row-major

// ---- prep stage 1: T = A*A (A = C^T), plus l2 term and accumulator init ----
// T[i][j] = sum_k A[i][k]*A[k][j] = sum_k C[k][i]*C[j][k]
__global__ __launch_bounds__(256) void prep_p1(const float* __restrict__ C,
                                               float* __restrict__ T,
                                               float* __restrict__ accum,
                                               unsigned* __restrict__ counter) {
  int e = blockIdx.x * 256 + threadIdx.x;    // 64 WGs * 256 = 16384 elements
  int i = e >> 7, j = e & 127;
  const float* Ci = C + i;                   // C[k][i], stride H — wave-broadcast (i uniform per wave)
  const float* Cj = C + j * H;               // own row, stride 1
  float s = 0.f;
  #pragma unroll 8
  for (int k = 0; k < H; k++) s += Ci[k * H] * Cj[k];
  T[e] = s;

  if (blockIdx.x == 0) {
    float l2 = 0.f;
    for (int q = threadIdx.x; q < H * H; q += 256) {
      float c = C[q], c2 = c * c;
      l2 += c2 * c2;                         // sum C^4
    }
    #pragma unroll
    for (int off = 32; off > 0; off >>= 1) l2 += __shfl_down(l2, off);
    __shared__ float red[4];
    if ((threadIdx.x & 63) == 0) red[threadIdx.x >> 6] = l2;
    __syncthreads();
    if (threadIdx.x == 0) {
      accum[0] = 0.f;
      accum[1] = red[0] + red[1] + red[2] + red[3];
      counter[0] = 0u;
    }
  }
}

// ---- prep stage 2: D = A + T/2 + (T*A)/6 + (T*T)/24, packed to MFMA B-frag layout ----
// (T*A)[i][j] = sum_k T[i][k]*C[j][k];  (T*T)[i][j] = sum_k T[i][k]*T[k][j]
__global__ __launch_bounds__(256) void prep_p2(const float* __restrict__ C,
                                               const float* __restrict__ T,
                                               __bf16* __restrict__ Dpack) {
  int e = blockIdx.x * 256 + threadIdx.x;
  int i = e >> 7, j = e & 127;
  const float* Ti = T + i * H;               // wave-broadcast row
  const float* Cj = C + j * H;               // own row
  const float* Tj = T + j;                   // column — lane-coalesced across j
  float s3 = 0.f, s4 = 0.f;
  #pragma unroll 8
  for (int k = 0; k < H; k++) {
    float t = Ti[k];
    s3 += t * Cj[k];
    s4 += t * Tj[k * H];
  }
  float d = C[j * H + i] + 0.5f * Ti[j] + s3 * (1.f / 6.f) + s4 * (1.f / 24.f);
  // pack: frag(kt,n), lane lanep, elem je holds D[kt*32 + (lanep>>4)*8 + je][n*16 + (lanep&15)]
  int kt = i >> 5, lq = (i >> 3) & 3, je = i & 7;
  int n = j >> 4, mm = j & 15;
  int lanep = lq * 16 + mm;
  Dpack[(size_t)(((kt * 8 + n) * 64 + lanep) * 8 + je)] = (__bf16)d;
}

// ---- main streaming pass: P = y*D via MFMA, residual + square + reduce;
//      last WG (ticket) writes the final scalar ----
__global__ __launch_bounds__(256, 2) void sindy_main(const float* __restrict__ x,
                                                     const __bf16* __restrict__ Dpack,
                                                     float* __restrict__ accum,
                                                     unsigned* __restrict__ counter,
                                                     float* __restrict__ out) {
  int lane = threadIdx.x & 63;
  int wave = threadIdx.x >> 6;
  int m = lane & 15, quad = lane >> 4;

  // register-resident B fragments (32 frags x 16B = 128 VGPRs), coalesced load
  bf16x8_t bfr[32];
  const bf16x8_t* Dp = (const bf16x8_t*)Dpack;
  #pragma unroll
  for (int f = 0; f < 32; f++) bfr[f] = Dp[f * 64 + lane];

  float lsum = 0.f;

  for (int tile = blockIdx.x; tile < 4096; tile += gridDim.x) {
    int b = tile >> 4;
    int ts = (tile & 15) << 6;               // s-base of 64-row tile
    int gb = b << 10;

    // A fragments: row sA = ts + wave*16 + m (always < 1024), k = kt*32 + quad*8 + j
    int sA = ts + (wave << 4) + m;
    const float* rp = x + (size_t)(gb + sA) * H + (quad << 3);
    bf16x8_t af[4];
    #pragma unroll
    for (int kt = 0; kt < 4; kt++) {
      floatx4_t u = *(const floatx4_t*)(rp + kt * 32);
      floatx4_t v = *(const floatx4_t*)(rp + kt * 32 + 4);
      bf16x8_t a;
      a[0] = (__bf16)u[0]; a[1] = (__bf16)u[1]; a[2] = (__bf16)u[2]; a[3] = (__bf16)u[3];
      a[4] = (__bf16)v[0]; a[5] = (__bf16)v[1]; a[6] = (__bf16)v[2]; a[7] = (__bf16)v[3];
      af[kt] = a;
    }

    floatx4_t acc[8];
    #pragma unroll
    for (int n = 0; n < 8; n++) acc[n] = (floatx4_t){0.f, 0.f, 0.f, 0.f};
    #pragma unroll
    for (int kt = 0; kt < 4; kt++)
      #pragma unroll
      for (int n = 0; n < 8; n++)
        acc[n] = __builtin_amdgcn_mfma_f32_16x16x32_bf16(af[kt], bfr[kt * 8 + n], acc[n], 0, 0, 0);

    // residual: C/D layout row = quad*4 + i2, col = n*16 + m
    int s0 = ts + (wave << 4) + (quad << 2);
    #pragma unroll
    for (int i2 = 0; i2 < 4; i2++) {
      int s = s0 + i2;
      int gy = gb + s;
      int gx1 = gy + 1; if (gx1 > NROWS_TOTAL - 1) gx1 = NROWS_TOTAL - 1;
      const float* yr = x + (size_t)gy * H + m;
      const float* x1r = x + (size_t)gx1 * H + m;
      if (s <= SEQ - 2) {
        #pragma unroll
        for (int n = 0; n < 8; n++) {
          float r = (yr[n * 16] - x1r[n * 16]) + acc[n][i2];
          lsum += r * r;
        }
      }
    }
  }

  #pragma unroll
  for (int off = 32; off > 0; off >>= 1) lsum += __shfl_down(lsum, off);
  __shared__ float red[4];
  if (lane == 0) red[wave] = lsum;
  __syncthreads();
  if (threadIdx.x == 0) {
    atomicAdd(accum, red[0] + red[1] + red[2] + red[3]);
    __threadfence();                         // make the add visible device-wide
    unsigned t = atomicAdd(counter, 1u);
    if (t == (unsigned)(gridDim.x - 1)) {    // last WG to finish: finalize
      float step = atomicAdd(accum, 0.f);    // L2-coherent read
      float l2 = atomicAdd(accum + 1, 0.f);
      out[0] = step * (1.0f / STEP_ELEMS) + 0.001f * l2 * (1.0f / 16384.0f);
    }
  }
}

extern "C" void kernel_launch(void* const* d_in, const int* in_sizes, int n_in,
                              void* d_out, int out_size, void* d_ws, size_t ws_size,
                              hipStream_t stream) {
  const float* x = (const float*)d_in[0];
  const float* C = (const float*)d_in[1];
  __bf16* Dpack = (__bf16*)d_ws;
  float* accum = (float*)((char*)d_ws + 32768);
  unsigned* counter = (unsigned*)((char*)d_ws + 32776);
  float* T = (float*)((char*)d_ws + 65536);
  float* out = (float*)d_out;

  prep_p1<<<64, 256, 0, stream>>>(C, T, accum, counter);
  prep_p2<<<64, 256, 0, stream>>>(C, T, Dpack);
  sindy_main<<<MAIN_WGS, 256, 0, stream>>>(x, Dpack, accum, counter, out);
}

// Round 4
// 219.951 us; speedup vs baseline: 1.0593x; 1.0593x over previous
//
#include <hip/hip_runtime.h>
#include <hip/hip_bf16.h>

typedef __bf16 bf16x8_t __attribute__((ext_vector_type(8)));
typedef float floatx4_t __attribute__((ext_vector_type(4)));

#define H 128
#define BATCH 256
#define SEQ 1024
#define NROWS_TOTAL (BATCH * SEQ)            // 262144 rows of x
#define STEP_ELEMS 33521664.0f               // 256*1023*128

// ws layout: [0, 32768)      : Dpack, bf16, MFMA-B-fragment order [kt][n][lane][j]
//            [32768, 32776)  : accum[2] = {step_sum, l2_sum}
//            [65536, 131072) : T = A*A, fp32 row-major
//
// Algebra: f(y)=y@C.T is linear, so RK4 collapses to y1 = y·(I + D),
// D = A + A^2/2 + A^3/6 + A^4/24, A = C^T (truncated expm). Main pass is one
// streaming GEMM P = y·D (bf16 MFMA on the small correction; residual (y-x1)
// kept in exact fp32), reading x exactly once: 537 MB → HBM-bound floor ~77 µs.

// ---- prep stage 1: T = A*A (A = C^T), plus l2 term and accumulator init ----
// T[i][j] = sum_k A[i][k]*A[k][j] = sum_k C[k][i]*C[j][k]
__global__ __launch_bounds__(256) void prep_p1(const float* __restrict__ C,
                                               float* __restrict__ T,
                                               float* __restrict__ accum) {
  int e = blockIdx.x * 256 + threadIdx.x;    // 64 WGs * 256 = 16384 elements
  int i = e >> 7, j = e & 127;
  const float* Ci = C + i;                   // C[k][i], stride H — wave-broadcast (i uniform per wave)
  const float* Cj = C + j * H;               // own row, stride 1
  float s = 0.f;
  #pragma unroll 8
  for (int k = 0; k < H; k++) s += Ci[k * H] * Cj[k];
  T[e] = s;

  if (blockIdx.x == 0) {
    float l2 = 0.f;
    for (int q = threadIdx.x; q < H * H; q += 256) {
      float c = C[q], c2 = c * c;
      l2 += c2 * c2;                         // sum C^4
    }
    #pragma unroll
    for (int off = 32; off > 0; off >>= 1) l2 += __shfl_down(l2, off);
    __shared__ float red[4];
    if ((threadIdx.x & 63) == 0) red[threadIdx.x >> 6] = l2;
    __syncthreads();
    if (threadIdx.x == 0) {
      accum[0] = 0.f;
      accum[1] = red[0] + red[1] + red[2] + red[3];
    }
  }
}

// ---- prep stage 2: D = A + T/2 + (T*A)/6 + (T*T)/24, packed to MFMA B-frag layout ----
// (T*A)[i][j] = sum_k T[i][k]*C[j][k];  (T*T)[i][j] = sum_k T[i][k]*T[k][j]
__global__ __launch_bounds__(256) void prep_p2(const float* __restrict__ C,
                                               const float* __restrict__ T,
                                               __bf16* __restrict__ Dpack) {
  int e = blockIdx.x * 256 + threadIdx.x;
  int i = e >> 7, j = e & 127;
  const float* Ti = T + i * H;               // wave-broadcast row
  const float* Cj = C + j * H;               // own row
  const float* Tj = T + j;                   // column — lane-coalesced across j
  float s3 = 0.f, s4 = 0.f;
  #pragma unroll 8
  for (int k = 0; k < H; k++) {
    float t = Ti[k];
    s3 += t * Cj[k];
    s4 += t * Tj[k * H];
  }
  float d = C[j * H + i] + 0.5f * Ti[j] + s3 * (1.f / 6.f) + s4 * (1.f / 24.f);
  // pack: frag(kt,n), lane lanep, elem je holds D[kt*32 + (lanep>>4)*8 + je][n*16 + (lanep&15)]
  int kt = i >> 5, lq = (i >> 3) & 3, je = i & 7;
  int n = j >> 4, mm = j & 15;
  int lanep = lq * 16 + mm;
  Dpack[(size_t)(((kt * 8 + n) * 64 + lanep) * 8 + je)] = (__bf16)d;
}

// ---- main streaming pass: P = y*D via MFMA, residual + square + reduce ----
__global__ __launch_bounds__(256, 2) void sindy_main(const float* __restrict__ x,
                                                     const __bf16* __restrict__ Dpack,
                                                     float* __restrict__ accum) {
  int lane = threadIdx.x & 63;
  int wave = threadIdx.x >> 6;
  int m = lane & 15, quad = lane >> 4;

  // register-resident B fragments (32 frags x 16B = 128 VGPRs), coalesced load
  bf16x8_t bfr[32];
  const bf16x8_t* Dp = (const bf16x8_t*)Dpack;
  #pragma unroll
  for (int f = 0; f < 32; f++) bfr[f] = Dp[f * 64 + lane];

  float lsum = 0.f;

  for (int tile = blockIdx.x; tile < 4096; tile += gridDim.x) {
    int b = tile >> 4;
    int ts = (tile & 15) << 6;               // s-base of 64-row tile
    int gb = b << 10;

    // A fragments: row sA = ts + wave*16 + m (always < 1024), k = kt*32 + quad*8 + j
    int sA = ts + (wave << 4) + m;
    const float* rp = x + (size_t)(gb + sA) * H + (quad << 3);
    bf16x8_t af[4];
    #pragma unroll
    for (int kt = 0; kt < 4; kt++) {
      floatx4_t u = *(const floatx4_t*)(rp + kt * 32);
      floatx4_t v = *(const floatx4_t*)(rp + kt * 32 + 4);
      bf16x8_t a;
      a[0] = (__bf16)u[0]; a[1] = (__bf16)u[1]; a[2] = (__bf16)u[2]; a[3] = (__bf16)u[3];
      a[4] = (__bf16)v[0]; a[5] = (__bf16)v[1]; a[6] = (__bf16)v[2]; a[7] = (__bf16)v[3];
      af[kt] = a;
    }

    floatx4_t acc[8];
    #pragma unroll
    for (int n = 0; n < 8; n++) acc[n] = (floatx4_t){0.f, 0.f, 0.f, 0.f};
    #pragma unroll
    for (int kt = 0; kt < 4; kt++)
      #pragma unroll
      for (int n = 0; n < 8; n++)
        acc[n] = __builtin_amdgcn_mfma_f32_16x16x32_bf16(af[kt], bfr[kt * 8 + n], acc[n], 0, 0, 0);

    // residual: C/D layout row = quad*4 + i2, col = n*16 + m (re-reads hit L1/L2)
    int s0 = ts + (wave << 4) + (quad << 2);
    #pragma unroll
    for (int i2 = 0; i2 < 4; i2++) {
      int s = s0 + i2;
      int gy = gb + s;
      int gx1 = gy + 1; if (gx1 > NROWS_TOTAL - 1) gx1 = NROWS_TOTAL - 1;
      const float* yr = x + (size_t)gy * H + m;
      const float* x1r = x + (size_t)gx1 * H + m;
      if (s <= SEQ - 2) {
        #pragma unroll
        for (int n = 0; n < 8; n++) {
          float r = (yr[n * 16] - x1r[n * 16]) + acc[n][i2];
          lsum += r * r;
        }
      }
    }
  }

  #pragma unroll
  for (int off = 32; off > 0; off >>= 1) lsum += __shfl_down(lsum, off);
  __shared__ float red[4];
  if (lane == 0) red[wave] = lsum;
  __syncthreads();
  if (threadIdx.x == 0) atomicAdd(accum, red[0] + red[1] + red[2] + red[3]);
}

__global__ void finalize_kernel(const float* __restrict__ accum, float* __restrict__ out) {
  out[0] = accum[0] * (1.0f / STEP_ELEMS) + 0.001f * accum[1] * (1.0f / 16384.0f);
}

extern "C" void kernel_launch(void* const* d_in, const int* in_sizes, int n_in,
                              void* d_out, int out_size, void* d_ws, size_t ws_size,
                              hipStream_t stream) {
  const float* x = (const float*)d_in[0];
  const float* C = (const float*)d_in[1];
  __bf16* Dpack = (__bf16*)d_ws;
  float* accum = (float*)((char*)d_ws + 32768);
  float* T = (float*)((char*)d_ws + 65536);
  float* out = (float*)d_out;

  prep_p1<<<64, 256, 0, stream>>>(C, T, accum);
  prep_p2<<<64, 256, 0, stream>>>(C, T, Dpack);
  sindy_main<<<512, 256, 0, stream>>>(x, Dpack, accum);
  finalize_kernel<<<1, 1, 0, stream>>>(accum, out);
}